// Round 1
// baseline (1598.203 us; speedup 1.0000x reference)
//
#include <hip/hip_runtime.h>

#define CDIM 700     // 2 heads * 350 units, head-concat
#define UHALF 350
#define BM 64
#define BN 64
#define BK 16

// ---------------- weight packing ----------------
// K: (2, Fin, 350) -> B: (Fin, 700) row-major, columns head-concat
__global__ void pack_weights(const float* __restrict__ K, float* __restrict__ B, int Fin) {
    long i = (long)blockIdx.x * blockDim.x + threadIdx.x;
    long total = (long)Fin * CDIM;
    if (i >= total) return;
    int f = (int)(i / CDIM), c = (int)(i % CDIM);
    int h = c / UHALF, u = c % UHALF;
    B[i] = K[((long)h * Fin + f) * UHALF + u];
}

// A: (2, 700, 1) -> asrc[700], adst[700] (head-concat over 350)
__global__ void pack_avec(const float* __restrict__ A, float* __restrict__ asrc, float* __restrict__ adst) {
    int i = blockIdx.x * blockDim.x + threadIdx.x;
    if (i >= CDIM) return;
    int h = i / UHALF, u = i % UHALF;
    asrc[i] = A[h * 2 * UHALF + u];
    adst[i] = A[h * 2 * UHALF + UHALF + u];
}

// ---------------- CSR build (by src) ----------------
__global__ void count_kernel(const int* __restrict__ edges, int* __restrict__ cnt, int E) {
    int e = blockIdx.x * blockDim.x + threadIdx.x;
    if (e >= E) return;
    atomicAdd(&cnt[edges[2 * e]], 1);
}

__global__ void scan_kernel(const int* __restrict__ cnt, int* __restrict__ offs, int Nn) {
    __shared__ int part[1024];
    int tid = threadIdx.x;
    int chunk = (Nn + 1023) / 1024;
    int b = tid * chunk;
    int e = min(b + chunk, Nn);
    int s = 0;
    for (int i = b; i < e; ++i) s += cnt[i];
    part[tid] = s;
    __syncthreads();
    for (int d = 1; d < 1024; d <<= 1) {
        int v = (tid >= d) ? part[tid - d] : 0;
        __syncthreads();
        part[tid] += v;
        __syncthreads();
    }
    int pre = (tid == 0) ? 0 : part[tid - 1];
    for (int i = b; i < e; ++i) { offs[i] = pre; pre += cnt[i]; }
    if (tid == 0) offs[Nn] = part[1023];
}

__global__ void fill_kernel(const int* __restrict__ edges, const int* __restrict__ offs,
                            int* __restrict__ fill, int* __restrict__ csr_dst, int E) {
    int e = blockIdx.x * blockDim.x + threadIdx.x;
    if (e >= E) return;
    int s = edges[2 * e], d = edges[2 * e + 1];
    int pos = offs[s] + atomicAdd(&fill[s], 1);
    csr_dst[pos] = d;
}

// ---------------- fp32 tiled GEMM: Hout(MxNc) = X(MxK) @ B(KxNc) ----------------
__global__ __launch_bounds__(256) void gemm_f32(const float* __restrict__ X, const float* __restrict__ B,
                                                float* __restrict__ Hout, int M, int K, int Nc) {
    __shared__ float sA[BK][BM + 1];
    __shared__ float sB[BK][BN + 1];
    int tid = threadIdx.x;
    int tx = tid % 16, ty = tid / 16;
    int brow = blockIdx.x * BM;
    int bcol = blockIdx.y * BN;
    float acc[4][4] = {};
    for (int k0 = 0; k0 < K; k0 += BK) {
        for (int i = tid; i < BM * BK; i += 256) {
            int r = i / BK, c = i % BK;
            int gr = brow + r, gk = k0 + c;
            sA[c][r] = (gr < M && gk < K) ? X[(long)gr * K + gk] : 0.f;
        }
        for (int i = tid; i < BK * BN; i += 256) {
            int r = i / BN, c = i % BN;
            int gk = k0 + r, gc = bcol + c;
            sB[r][c] = (gk < K && gc < Nc) ? B[(long)gk * Nc + gc] : 0.f;
        }
        __syncthreads();
#pragma unroll
        for (int kk = 0; kk < BK; ++kk) {
            float a[4], b[4];
#pragma unroll
            for (int i = 0; i < 4; ++i) a[i] = sA[kk][ty * 4 + i];
#pragma unroll
            for (int j = 0; j < 4; ++j) b[j] = sB[kk][tx * 4 + j];
#pragma unroll
            for (int i = 0; i < 4; ++i)
#pragma unroll
                for (int j = 0; j < 4; ++j) acc[i][j] += a[i] * b[j];
        }
        __syncthreads();
    }
    for (int i = 0; i < 4; ++i) {
        int gr = brow + ty * 4 + i;
        if (gr >= M) continue;
        for (int j = 0; j < 4; ++j) {
            int gc = bcol + tx * 4 + j;
            if (gc < Nc) Hout[(long)gr * Nc + gc] = acc[i][j];
        }
    }
}

// ---------------- per-node attention scores s_src/s_dst ----------------
__global__ __launch_bounds__(256) void score_kernel(const float* __restrict__ Hm, const float* __restrict__ asrc,
                                                    const float* __restrict__ adst, float* __restrict__ s_src,
                                                    float* __restrict__ s_dst, int Nn) {
    int wave = threadIdx.x >> 6, lane = threadIdx.x & 63;
    int u = blockIdx.x * 4 + wave;
    if (u >= Nn) return;
    const float* hrow = Hm + (long)u * CDIM;
    for (int h = 0; h < 2; ++h) {
        float ps = 0.f, pd = 0.f;
        for (int c = lane; c < UHALF; c += 64) {
            float v = hrow[h * UHALF + c];
            ps += v * asrc[h * UHALF + c];
            pd += v * adst[h * UHALF + c];
        }
        for (int d = 32; d; d >>= 1) { ps += __shfl_down(ps, d); pd += __shfl_down(pd, d); }
        if (lane == 0) { s_src[(long)h * Nn + u] = ps; s_dst[(long)h * Nn + u] = pd; }
    }
}

// ---------------- per-node aggregation (one block per node) ----------------
__global__ __launch_bounds__(256) void aggregate_kernel(const float* __restrict__ Hm, const float* __restrict__ s_src,
                                                        const float* __restrict__ s_dst, const int* __restrict__ offs,
                                                        const int* __restrict__ csr_dst, float* __restrict__ Y, int Nn) {
    int u = blockIdx.x;
    int tid = threadIdx.x;
    int beg = offs[u], end = offs[u + 1];
    __shared__ float w_s[2][64];
    __shared__ int dst_s[64];
    float acc0 = 0.f, acc1 = 0.f, acc2 = 0.f;
    float den0 = 0.f, den1 = 0.f;
    int c1 = tid + 256, c2 = tid + 512;
    int h1 = (c1 < UHALF) ? 0 : 1;
    float ss0 = s_src[u];
    float ss1 = s_src[Nn + u];
    for (int base = beg; base < end; base += 64) {
        int mchunk = min(64, end - base);
        if (tid < mchunk) {
            int v = csr_dst[base + tid];
            dst_s[tid] = v;
            float x0 = ss0 + s_dst[v];
            float x1 = ss1 + s_dst[Nn + v];
            x0 = (x0 >= 0.f) ? x0 : 0.2f * x0;
            x1 = (x1 >= 0.f) ? x1 : 0.2f * x1;
            x0 = fminf(fmaxf(x0, -2.f), 2.f);
            x1 = fminf(fmaxf(x1, -2.f), 2.f);
            w_s[0][tid] = expf(x0);
            w_s[1][tid] = expf(x1);
        }
        __syncthreads();
        for (int j = 0; j < mchunk; ++j) {
            int v = dst_s[j];
            const float* hv = Hm + (long)v * CDIM;
            float w0 = w_s[0][j], w1 = w_s[1][j];
            den0 += w0;
            den1 += w1;
            acc0 += hv[tid] * w0;
            acc1 += hv[c1] * (h1 ? w1 : w0);
            if (c2 < CDIM) acc2 += hv[c2] * w1;
        }
        __syncthreads();
    }
    float inv0 = (den0 > 0.f) ? 1.f / den0 : 0.f;
    float inv1 = (den1 > 0.f) ? 1.f / den1 : 0.f;
    float* yrow = Y + (long)u * CDIM;
    yrow[tid] = fmaxf(acc0 * inv0, 0.f);
    yrow[c1] = fmaxf(acc1 * (h1 ? inv1 : inv0), 0.f);
    if (c2 < CDIM) yrow[c2] = fmaxf(acc2 * inv1, 0.f);
}

// ---------------- decoder: out[m] = sum_c |O[r,c]-O[c,c]| * w[c] + b ----------------
__global__ __launch_bounds__(256) void decode_kernel(const float* __restrict__ O, const int* __restrict__ r_idx,
                                                     const int* __restrict__ c_idx, const float* __restrict__ dec_w,
                                                     const float* __restrict__ dec_b, float* __restrict__ out, int M) {
    int wave = threadIdx.x >> 6, lane = threadIdx.x & 63;
    long m = (long)blockIdx.x * 4 + wave;
    if (m >= M) return;
    int r = r_idx[m], c = c_idx[m];
    const float* orow = O + (long)r * CDIM;
    const float* crow = O + (long)c * CDIM;
    float s = 0.f;
    for (int j = lane; j < CDIM; j += 64) s += fabsf(orow[j] - crow[j]) * dec_w[j];
    for (int d = 32; d; d >>= 1) s += __shfl_down(s, d);
    if (lane == 0) out[m] = s + dec_b[0];
}

extern "C" void kernel_launch(void* const* d_in, const int* in_sizes, int n_in,
                              void* d_out, int out_size, void* d_ws, size_t ws_size,
                              hipStream_t stream) {
    (void)n_in; (void)out_size; (void)ws_size;
    const float* node_feats = (const float*)d_in[0];
    const int* edges = (const int*)d_in[1];
    const int* r_idx = (const int*)d_in[2];
    const int* c_idx = (const int*)d_in[3];
    const float* kmats[3] = {(const float*)d_in[4], (const float*)d_in[6], (const float*)d_in[8]};
    const float* amats[3] = {(const float*)d_in[5], (const float*)d_in[7], (const float*)d_in[9]};
    const float* dec_w = (const float*)d_in[10];
    const float* dec_b = (const float*)d_in[11];
    float* out = (float*)d_out;

    const int F0 = 256;
    const int N = in_sizes[0] / F0;
    const int E = in_sizes[1] / 2;
    const int M = in_sizes[2];

    char* ws = (char*)d_ws;
    size_t off = 0;
    auto alloc = [&](size_t bytes) -> void* {
        void* p = ws + off;
        off += (bytes + 255) & ~(size_t)255;
        return p;
    };
    float* hbuf = (float*)alloc((size_t)N * CDIM * 4);
    float* Ybuf = (float*)alloc((size_t)N * CDIM * 4);
    float* Bpack = (float*)alloc((size_t)CDIM * CDIM * 4);
    float* asrc = (float*)alloc(CDIM * 4);
    float* adst = (float*)alloc(CDIM * 4);
    float* s_src = (float*)alloc((size_t)2 * N * 4);
    float* s_dst = (float*)alloc((size_t)2 * N * 4);
    int* offs = (int*)alloc((size_t)(N + 1) * 4);
    int* cnt = (int*)alloc((size_t)N * 4);
    int* fill = (int*)alloc((size_t)N * 4);
    int* csr_dst = (int*)alloc((size_t)E * 4);

    hipMemsetAsync(cnt, 0, (size_t)N * 4, stream);
    hipMemsetAsync(fill, 0, (size_t)N * 4, stream);

    count_kernel<<<(E + 255) / 256, 256, 0, stream>>>(edges, cnt, E);
    scan_kernel<<<1, 1024, 0, stream>>>(cnt, offs, N);
    fill_kernel<<<(E + 255) / 256, 256, 0, stream>>>(edges, offs, fill, csr_dst, E);

    const float* X = node_feats;
    int Fin = F0;
    for (int l = 0; l < 3; ++l) {
        long bt = (long)Fin * CDIM;
        pack_weights<<<(int)((bt + 255) / 256), 256, 0, stream>>>(kmats[l], Bpack, Fin);
        pack_avec<<<(CDIM + 255) / 256, 256, 0, stream>>>(amats[l], asrc, adst);
        dim3 g((N + BM - 1) / BM, (CDIM + BN - 1) / BN);
        gemm_f32<<<g, 256, 0, stream>>>(X, Bpack, hbuf, N, Fin, CDIM);
        score_kernel<<<(N + 3) / 4, 256, 0, stream>>>(hbuf, asrc, adst, s_src, s_dst, N);
        aggregate_kernel<<<N, 256, 0, stream>>>(hbuf, s_src, s_dst, offs, csr_dst, Ybuf, N);
        X = Ybuf;
        Fin = CDIM;
    }
    decode_kernel<<<(M + 3) / 4, 256, 0, stream>>>(Ybuf, r_idx, c_idx, dec_w, dec_b, out, M);
}

// Round 2
// 595.532 us; speedup vs baseline: 2.6837x; 2.6837x over previous
//
#include <hip/hip_runtime.h>

#define CDIM 700     // 2 heads * 350 units, head-concat
#define UHALF 350
#define NPAD 768     // CDIM padded to multiple of 128

// GEMM tile params
#define GBM 128
#define GBN 128
#define GBK 32

typedef __attribute__((ext_vector_type(8))) short bf16x8;
typedef __attribute__((ext_vector_type(4))) float f32x4;

__device__ inline short f2bf(float v) {
    unsigned u = __float_as_uint(v);
    unsigned r = (u + 0x7fffu + ((u >> 16) & 1u)) >> 16;
    return (short)r;
}

__device__ inline void load_lds16(const void* g, void* l) {
    __builtin_amdgcn_global_load_lds(
        (const __attribute__((address_space(1))) unsigned*)g,
        (__attribute__((address_space(3))) unsigned*)l,
        16, 0, 0);
}

// ---------------- packing / conversion ----------------
// K: (2, Fin, 350) -> Bt: (768, Kpad) bf16, Bt[c][f] = K[h][f][u], zero-padded
__global__ void pack_bt(const float* __restrict__ K, short* __restrict__ Bt, int Kin, int Kpad) {
    long i = (long)blockIdx.x * blockDim.x + threadIdx.x;
    long total = (long)NPAD * Kpad;
    if (i >= total) return;
    int c = (int)(i / Kpad), f = (int)(i % Kpad);
    float v = 0.f;
    if (c < CDIM && f < Kin) {
        int h = c / UHALF, u = c % UHALF;
        v = K[((long)h * Kin + f) * UHALF + u];
    }
    Bt[i] = f2bf(v);
}

// X fp32 (M x Kin) -> Xb bf16 (M x Kpad), zero-padded cols
__global__ void cvt_bf16(const float* __restrict__ X, short* __restrict__ Xb, int M, int Kin, int Kpad) {
    long i = (long)blockIdx.x * blockDim.x + threadIdx.x;
    long total = (long)M * Kpad;
    if (i >= total) return;
    int r = (int)(i / Kpad), c = (int)(i % Kpad);
    Xb[i] = (c < Kin) ? f2bf(X[(long)r * Kin + c]) : (short)0;
}

// A: (2, 700, 1) -> asrc[700], adst[700] (head-concat over 350)
__global__ void pack_avec(const float* __restrict__ A, float* __restrict__ asrc, float* __restrict__ adst) {
    int i = blockIdx.x * blockDim.x + threadIdx.x;
    if (i >= CDIM) return;
    int h = i / UHALF, u = i % UHALF;
    asrc[i] = A[h * 2 * UHALF + u];
    adst[i] = A[h * 2 * UHALF + UHALF + u];
}

// ---------------- CSR build (by src) ----------------
__global__ void count_kernel(const int* __restrict__ edges, int* __restrict__ cnt, int E) {
    int e = blockIdx.x * blockDim.x + threadIdx.x;
    if (e >= E) return;
    atomicAdd(&cnt[edges[2 * e]], 1);
}

__global__ void scan_kernel(const int* __restrict__ cnt, int* __restrict__ offs, int Nn) {
    __shared__ int part[1024];
    int tid = threadIdx.x;
    int chunk = (Nn + 1023) / 1024;
    int b = tid * chunk;
    int e = min(b + chunk, Nn);
    int s = 0;
    for (int i = b; i < e; ++i) s += cnt[i];
    part[tid] = s;
    __syncthreads();
    for (int d = 1; d < 1024; d <<= 1) {
        int v = (tid >= d) ? part[tid - d] : 0;
        __syncthreads();
        part[tid] += v;
        __syncthreads();
    }
    int pre = (tid == 0) ? 0 : part[tid - 1];
    for (int i = b; i < e; ++i) { offs[i] = pre; pre += cnt[i]; }
    if (tid == 0) offs[Nn] = part[1023];
}

__global__ void fill_kernel(const int* __restrict__ edges, const int* __restrict__ offs,
                            int* __restrict__ fill, int* __restrict__ csr_dst, int E) {
    int e = blockIdx.x * blockDim.x + threadIdx.x;
    if (e >= E) return;
    int s = edges[2 * e], d = edges[2 * e + 1];
    int pos = offs[s] + atomicAdd(&fill[s], 1);
    csr_dst[pos] = d;
}

// ---------------- bf16 MFMA GEMM: Hout(M x 700) = Xb(M x Kpad) @ Bt^T ----------------
// Xb: [M][Kpad] bf16. Bt: [NPAD][Kpad] bf16 (column-major of B). Hout fp32 [M][700].
__global__ __launch_bounds__(256) void gemm_mfma(const short* __restrict__ Xb, const short* __restrict__ Bt,
                                                 float* __restrict__ Hout, int M, int Kpad, int Ncols) {
    __shared__ short sA[GBM * GBK];   // [row][k], 64B per row
    __shared__ short sB[GBN * GBK];   // [col][k]
    int tid = threadIdx.x;
    int wave = tid >> 6, lane = tid & 63;
    int brow = blockIdx.x * GBM;
    int bcol = blockIdx.y * GBN;
    int wr = wave >> 1, wc = wave & 1;   // wave sub-tile 64x64 at (wr*64, wc*64)
    f32x4 acc[4][4] = {};

    int lrow = lane >> 2;            // 0..15
    int lkb = (lane & 3) * 8;        // k offset 0/8/16/24

    for (int k0 = 0; k0 < Kpad; k0 += GBK) {
        // stage A: wave handles rows [wave*32, wave*32+32)
#pragma unroll
        for (int q = 0; q < 2; ++q) {
            int r0 = wave * 32 + q * 16;
            int grow = brow + r0 + lrow;
            if (grow >= M) grow = M - 1;
            const short* src = Xb + (long)grow * Kpad + k0 + lkb;
            load_lds16(src, &sA[r0 * GBK]);
        }
        // stage B: wave handles cols [wave*32, wave*32+32); NPAD padded, no clamp
#pragma unroll
        for (int q = 0; q < 2; ++q) {
            int c0 = wave * 32 + q * 16;
            const short* src = Bt + (long)(bcol + c0 + lrow) * Kpad + k0 + lkb;
            load_lds16(src, &sB[c0 * GBK]);
        }
        __syncthreads();   // drains vmcnt before barrier -> tiles ready

        const short* pa = sA + (wr * 64 + (lane & 15)) * GBK + (lane >> 4) * 8;
        const short* pb = sB + (wc * 64 + (lane & 15)) * GBK + (lane >> 4) * 8;
        bf16x8 af[4], bfr[4];
#pragma unroll
        for (int m = 0; m < 4; ++m) af[m] = *(const bf16x8*)(pa + m * 16 * GBK);
#pragma unroll
        for (int n = 0; n < 4; ++n) bfr[n] = *(const bf16x8*)(pb + n * 16 * GBK);
#pragma unroll
        for (int m = 0; m < 4; ++m)
#pragma unroll
            for (int n = 0; n < 4; ++n)
                acc[m][n] = __builtin_amdgcn_mfma_f32_16x16x32_bf16(af[m], bfr[n], acc[m][n], 0, 0, 0);
        __syncthreads();   // all reads done before next stage
    }

    int crow = brow + wr * 64 + (lane >> 4) * 4;
    int ccol = bcol + wc * 64 + (lane & 15);
#pragma unroll
    for (int m = 0; m < 4; ++m) {
#pragma unroll
        for (int r = 0; r < 4; ++r) {
            int gr = crow + m * 16 + r;
            if (gr >= M) continue;
#pragma unroll
            for (int n = 0; n < 4; ++n) {
                int gc = ccol + n * 16;
                if (gc < Ncols) Hout[(long)gr * Ncols + gc] = acc[m][n][r];
            }
        }
    }
}

// ---------------- per-node attention scores s_src/s_dst ----------------
__global__ __launch_bounds__(256) void score_kernel(const float* __restrict__ Hm, const float* __restrict__ asrc,
                                                    const float* __restrict__ adst, float* __restrict__ s_src,
                                                    float* __restrict__ s_dst, int Nn) {
    int wave = threadIdx.x >> 6, lane = threadIdx.x & 63;
    int u = blockIdx.x * 4 + wave;
    if (u >= Nn) return;
    const float* hrow = Hm + (long)u * CDIM;
    for (int h = 0; h < 2; ++h) {
        float ps = 0.f, pd = 0.f;
        for (int c = lane; c < UHALF; c += 64) {
            float v = hrow[h * UHALF + c];
            ps += v * asrc[h * UHALF + c];
            pd += v * adst[h * UHALF + c];
        }
        for (int d = 32; d; d >>= 1) { ps += __shfl_down(ps, d); pd += __shfl_down(pd, d); }
        if (lane == 0) { s_src[(long)h * Nn + u] = ps; s_dst[(long)h * Nn + u] = pd; }
    }
}

// ---------------- per-node aggregation (one block per node) ----------------
__global__ __launch_bounds__(256) void aggregate_kernel(const float* __restrict__ Hm, const float* __restrict__ s_src,
                                                        const float* __restrict__ s_dst, const int* __restrict__ offs,
                                                        const int* __restrict__ csr_dst, float* __restrict__ Y, int Nn) {
    int u = blockIdx.x;
    int tid = threadIdx.x;
    int beg = offs[u], end = offs[u + 1];
    __shared__ float w_s[2][64];
    __shared__ int dst_s[64];
    float acc0 = 0.f, acc1 = 0.f, acc2 = 0.f;
    float den0 = 0.f, den1 = 0.f;
    int c1 = tid + 256, c2 = tid + 512;
    int h1 = (c1 < UHALF) ? 0 : 1;
    float ss0 = s_src[u];
    float ss1 = s_src[Nn + u];
    for (int base = beg; base < end; base += 64) {
        int mchunk = min(64, end - base);
        if (tid < mchunk) {
            int v = csr_dst[base + tid];
            dst_s[tid] = v;
            float x0 = ss0 + s_dst[v];
            float x1 = ss1 + s_dst[Nn + v];
            x0 = (x0 >= 0.f) ? x0 : 0.2f * x0;
            x1 = (x1 >= 0.f) ? x1 : 0.2f * x1;
            x0 = fminf(fmaxf(x0, -2.f), 2.f);
            x1 = fminf(fmaxf(x1, -2.f), 2.f);
            w_s[0][tid] = expf(x0);
            w_s[1][tid] = expf(x1);
        }
        __syncthreads();
        for (int j = 0; j < mchunk; ++j) {
            int v = dst_s[j];
            const float* hv = Hm + (long)v * CDIM;
            float w0 = w_s[0][j], w1 = w_s[1][j];
            den0 += w0;
            den1 += w1;
            acc0 += hv[tid] * w0;
            acc1 += hv[c1] * (h1 ? w1 : w0);
            if (c2 < CDIM) acc2 += hv[c2] * w1;
        }
        __syncthreads();
    }
    float inv0 = (den0 > 0.f) ? 1.f / den0 : 0.f;
    float inv1 = (den1 > 0.f) ? 1.f / den1 : 0.f;
    float* yrow = Y + (long)u * CDIM;
    yrow[tid] = fmaxf(acc0 * inv0, 0.f);
    yrow[c1] = fmaxf(acc1 * (h1 ? inv1 : inv0), 0.f);
    if (c2 < CDIM) yrow[c2] = fmaxf(acc2 * inv1, 0.f);
}

// ---------------- decoder: out[m] = sum_c |O[r,c]-O[c,c]| * w[c] + b ----------------
__global__ __launch_bounds__(256) void decode_kernel(const float* __restrict__ O, const int* __restrict__ r_idx,
                                                     const int* __restrict__ c_idx, const float* __restrict__ dec_w,
                                                     const float* __restrict__ dec_b, float* __restrict__ out, int M) {
    int wave = threadIdx.x >> 6, lane = threadIdx.x & 63;
    long m = (long)blockIdx.x * 4 + wave;
    if (m >= M) return;
    int r = r_idx[m], c = c_idx[m];
    const float* orow = O + (long)r * CDIM;
    const float* crow = O + (long)c * CDIM;
    float s = 0.f;
    for (int j = lane; j < CDIM; j += 64) s += fabsf(orow[j] - crow[j]) * dec_w[j];
    for (int d = 32; d; d >>= 1) s += __shfl_down(s, d);
    if (lane == 0) out[m] = s + dec_b[0];
}

extern "C" void kernel_launch(void* const* d_in, const int* in_sizes, int n_in,
                              void* d_out, int out_size, void* d_ws, size_t ws_size,
                              hipStream_t stream) {
    (void)n_in; (void)out_size; (void)ws_size;
    const float* node_feats = (const float*)d_in[0];
    const int* edges = (const int*)d_in[1];
    const int* r_idx = (const int*)d_in[2];
    const int* c_idx = (const int*)d_in[3];
    const float* kmats[3] = {(const float*)d_in[4], (const float*)d_in[6], (const float*)d_in[8]};
    const float* amats[3] = {(const float*)d_in[5], (const float*)d_in[7], (const float*)d_in[9]};
    const float* dec_w = (const float*)d_in[10];
    const float* dec_b = (const float*)d_in[11];
    float* out = (float*)d_out;

    const int F0 = 256;
    const int N = in_sizes[0] / F0;
    const int E = in_sizes[1] / 2;
    const int M = in_sizes[2];
    const int KP1 = 256;   // layer-1 Kpad
    const int KP2 = 704;   // layers 2/3 Kpad (700 padded to 32)

    char* ws = (char*)d_ws;
    size_t off = 0;
    auto alloc = [&](size_t bytes) -> void* {
        void* p = ws + off;
        off += (bytes + 255) & ~(size_t)255;
        return p;
    };
    float* hbuf = (float*)alloc((size_t)N * CDIM * 4);
    float* Ybuf = (float*)alloc((size_t)N * CDIM * 4);
    short* Xb   = (short*)alloc((size_t)N * KP2 * 2);
    short* Bt   = (short*)alloc((size_t)NPAD * KP2 * 2);
    float* asrc = (float*)alloc(CDIM * 4);
    float* adst = (float*)alloc(CDIM * 4);
    float* s_src = (float*)alloc((size_t)2 * N * 4);
    float* s_dst = (float*)alloc((size_t)2 * N * 4);
    int* offs = (int*)alloc((size_t)(N + 1) * 4);
    int* cnt = (int*)alloc((size_t)N * 4);
    int* fill = (int*)alloc((size_t)N * 4);
    int* csr_dst = (int*)alloc((size_t)E * 4);

    hipMemsetAsync(cnt, 0, (size_t)N * 4, stream);
    hipMemsetAsync(fill, 0, (size_t)N * 4, stream);

    count_kernel<<<(E + 255) / 256, 256, 0, stream>>>(edges, cnt, E);
    scan_kernel<<<1, 1024, 0, stream>>>(cnt, offs, N);
    fill_kernel<<<(E + 255) / 256, 256, 0, stream>>>(edges, offs, fill, csr_dst, E);

    const float* X = node_feats;
    int Fin = F0;
    for (int l = 0; l < 3; ++l) {
        int Kpad = (l == 0) ? KP1 : KP2;
        long bt = (long)NPAD * Kpad;
        pack_bt<<<(int)((bt + 255) / 256), 256, 0, stream>>>(kmats[l], Bt, Fin, Kpad);
        pack_avec<<<(CDIM + 255) / 256, 256, 0, stream>>>(amats[l], asrc, adst);
        long xt = (long)N * Kpad;
        cvt_bf16<<<(int)((xt + 255) / 256), 256, 0, stream>>>(X, Xb, N, Fin, Kpad);
        dim3 g((N + GBM - 1) / GBM, NPAD / GBN);
        gemm_mfma<<<g, 256, 0, stream>>>(Xb, Bt, hbuf, N, Kpad, CDIM);
        score_kernel<<<(N + 3) / 4, 256, 0, stream>>>(hbuf, asrc, adst, s_src, s_dst, N);
        aggregate_kernel<<<N, 256, 0, stream>>>(hbuf, s_src, s_dst, offs, csr_dst, Ybuf, N);
        X = Ybuf;
        Fin = CDIM;
    }
    decode_kernel<<<(M + 3) / 4, 256, 0, stream>>>(Ybuf, r_idx, c_idx, dec_w, dec_b, out, M);
}

// Round 3
// 426.889 us; speedup vs baseline: 3.7438x; 1.3951x over previous
//
#include <hip/hip_runtime.h>

#define CDIM 700     // 2 heads * 350 units, head-concat
#define UHALF 350
#define NPAD 768     // CDIM padded to multiple of 128 (GEMM N dim)
#define HS 704       // activation row stride (bf16), 704 = 176*4

// GEMM tile params
#define GBM 128
#define GBN 128
#define GBK 32

typedef __attribute__((ext_vector_type(8))) short bf16x8;
typedef __attribute__((ext_vector_type(4))) float f32x4;

__device__ inline short f2bf(float v) {
    unsigned u = __float_as_uint(v);
    unsigned r = (u + 0x7fffu + ((u >> 16) & 1u)) >> 16;
    return (short)r;
}
__device__ inline float bf2f(short s) {
    return __uint_as_float(((unsigned)(unsigned short)s) << 16);
}

__device__ inline void load_lds16(const void* g, void* l) {
    __builtin_amdgcn_global_load_lds(
        (const __attribute__((address_space(1))) unsigned*)g,
        (__attribute__((address_space(3))) unsigned*)l,
        16, 0, 0);
}

// ---------------- packing / conversion ----------------
// K: (2, Fin, 350) -> Bt: (768, Kpad) bf16, Bt[c][f] = K[h][f][u], zero-padded
__global__ void pack_bt(const float* __restrict__ K, short* __restrict__ Bt, int Kin, int Kpad) {
    long i = (long)blockIdx.x * blockDim.x + threadIdx.x;
    long total = (long)NPAD * Kpad;
    if (i >= total) return;
    int c = (int)(i / Kpad), f = (int)(i % Kpad);
    float v = 0.f;
    if (c < CDIM && f < Kin) {
        int h = c / UHALF, u = c % UHALF;
        v = K[((long)h * Kin + f) * UHALF + u];
    }
    Bt[i] = f2bf(v);
}

// node_feats fp32 (N x 256) -> X0 bf16 (N x 256)
__global__ void cvt_bf16(const float* __restrict__ X, short* __restrict__ Xb, long total) {
    long i = (long)blockIdx.x * blockDim.x + threadIdx.x;
    if (i >= total) return;
    Xb[i] = f2bf(X[i]);
}

// A: (2, 700, 1) -> asrc[704], adst[704] zero-padded
__global__ void pack_avec(const float* __restrict__ A, float* __restrict__ asrc, float* __restrict__ adst) {
    int i = blockIdx.x * blockDim.x + threadIdx.x;
    if (i >= HS) return;
    if (i < CDIM) {
        int h = i / UHALF, u = i % UHALF;
        asrc[i] = A[h * 2 * UHALF + u];
        adst[i] = A[h * 2 * UHALF + UHALF + u];
    } else {
        asrc[i] = 0.f;
        adst[i] = 0.f;
    }
}

// dec_w (700) -> padded 704 fp32
__global__ void pack_decw(const float* __restrict__ w, float* __restrict__ wp) {
    int i = blockIdx.x * blockDim.x + threadIdx.x;
    if (i >= HS) return;
    wp[i] = (i < CDIM) ? w[i] : 0.f;
}

// ---------------- CSR build (by src) ----------------
__global__ void count_kernel(const int* __restrict__ edges, int* __restrict__ cnt, int E) {
    int e = blockIdx.x * blockDim.x + threadIdx.x;
    if (e >= E) return;
    atomicAdd(&cnt[edges[2 * e]], 1);
}

__global__ void scan_kernel(const int* __restrict__ cnt, int* __restrict__ offs, int Nn) {
    __shared__ int part[1024];
    int tid = threadIdx.x;
    int chunk = (Nn + 1023) / 1024;
    int b = tid * chunk;
    int e = min(b + chunk, Nn);
    int s = 0;
    for (int i = b; i < e; ++i) s += cnt[i];
    part[tid] = s;
    __syncthreads();
    for (int d = 1; d < 1024; d <<= 1) {
        int v = (tid >= d) ? part[tid - d] : 0;
        __syncthreads();
        part[tid] += v;
        __syncthreads();
    }
    int pre = (tid == 0) ? 0 : part[tid - 1];
    for (int i = b; i < e; ++i) { offs[i] = pre; pre += cnt[i]; }
    if (tid == 0) offs[Nn] = part[1023];
}

__global__ void fill_kernel(const int* __restrict__ edges, const int* __restrict__ offs,
                            int* __restrict__ fill, int* __restrict__ csr_dst, int E) {
    int e = blockIdx.x * blockDim.x + threadIdx.x;
    if (e >= E) return;
    int s = edges[2 * e], d = edges[2 * e + 1];
    int pos = offs[s] + atomicAdd(&fill[s], 1);
    csr_dst[pos] = d;
}

// ---------------- bf16 MFMA GEMM: hb(M x 704,bf16) = Xb(M x Kpad) @ Bt^T ----------------
__global__ __launch_bounds__(256) void gemm_mfma(const short* __restrict__ Xb, const short* __restrict__ Bt,
                                                 short* __restrict__ hb, int M, int Kpad) {
    __shared__ short sA[GBM * GBK];   // [row][k]
    __shared__ short sB[GBN * GBK];   // [col][k]
    int tid = threadIdx.x;
    int wave = tid >> 6, lane = tid & 63;
    int brow = blockIdx.x * GBM;
    int bcol = blockIdx.y * GBN;
    int wr = wave >> 1, wc = wave & 1;
    f32x4 acc[4][4] = {};

    int lrow = lane >> 2;
    int lkb = (lane & 3) * 8;

    for (int k0 = 0; k0 < Kpad; k0 += GBK) {
#pragma unroll
        for (int q = 0; q < 2; ++q) {
            int r0 = wave * 32 + q * 16;
            int grow = brow + r0 + lrow;
            if (grow >= M) grow = M - 1;
            const short* src = Xb + (long)grow * Kpad + k0 + lkb;
            load_lds16(src, &sA[r0 * GBK]);
        }
#pragma unroll
        for (int q = 0; q < 2; ++q) {
            int c0 = wave * 32 + q * 16;
            const short* src = Bt + (long)(bcol + c0 + lrow) * Kpad + k0 + lkb;
            load_lds16(src, &sB[c0 * GBK]);
        }
        __syncthreads();

        const short* pa = sA + (wr * 64 + (lane & 15)) * GBK + (lane >> 4) * 8;
        const short* pb = sB + (wc * 64 + (lane & 15)) * GBK + (lane >> 4) * 8;
        bf16x8 af[4], bfr[4];
#pragma unroll
        for (int m = 0; m < 4; ++m) af[m] = *(const bf16x8*)(pa + m * 16 * GBK);
#pragma unroll
        for (int n = 0; n < 4; ++n) bfr[n] = *(const bf16x8*)(pb + n * 16 * GBK);
#pragma unroll
        for (int m = 0; m < 4; ++m)
#pragma unroll
            for (int n = 0; n < 4; ++n)
                acc[m][n] = __builtin_amdgcn_mfma_f32_16x16x32_bf16(af[m], bfr[n], acc[m][n], 0, 0, 0);
        __syncthreads();
    }

    int crow = brow + wr * 64 + (lane >> 4) * 4;
    int ccol = bcol + wc * 64 + (lane & 15);
#pragma unroll
    for (int m = 0; m < 4; ++m) {
#pragma unroll
        for (int r = 0; r < 4; ++r) {
            int gr = crow + m * 16 + r;
            if (gr >= M) continue;
#pragma unroll
            for (int n = 0; n < 4; ++n) {
                int gc = ccol + n * 16;
                if (gc < CDIM) hb[(long)gr * HS + gc] = f2bf(acc[m][n][r]);
            }
        }
    }
}

// ---------------- per-node attention scores s_src/s_dst (reads bf16 hb) ----------------
__global__ __launch_bounds__(256) void score_kernel(const short* __restrict__ hb, const float* __restrict__ asrc,
                                                    const float* __restrict__ adst, float* __restrict__ s_src,
                                                    float* __restrict__ s_dst, int Nn) {
    int wave = threadIdx.x >> 6, lane = threadIdx.x & 63;
    int u = blockIdx.x * 4 + wave;
    if (u >= Nn) return;
    const short4* hrow = (const short4*)(hb + (long)u * HS);
    float ps0 = 0.f, pd0 = 0.f, ps1 = 0.f, pd1 = 0.f;
    for (int it = lane; it < HS / 4; it += 64) {
        short4 v = hrow[it];
        int col = it * 4;
#pragma unroll
        for (int e = 0; e < 4; ++e) {
            float f = bf2f(((const short*)&v)[e]);
            int c = col + e;
            float a = asrc[c], d = adst[c];
            if (c < UHALF) { ps0 += f * a; pd0 += f * d; }
            else           { ps1 += f * a; pd1 += f * d; }
        }
    }
    for (int d = 32; d; d >>= 1) {
        ps0 += __shfl_down(ps0, d); pd0 += __shfl_down(pd0, d);
        ps1 += __shfl_down(ps1, d); pd1 += __shfl_down(pd1, d);
    }
    if (lane == 0) {
        s_src[u] = ps0; s_dst[u] = pd0;
        s_src[Nn + u] = ps1; s_dst[Nn + u] = pd1;
    }
}

// ---------------- per-node aggregation (bf16 in, bf16 out with relu+pad) ----------------
__global__ __launch_bounds__(256) void aggregate_kernel(const short* __restrict__ hb, const float* __restrict__ s_src,
                                                        const float* __restrict__ s_dst, const int* __restrict__ offs,
                                                        const int* __restrict__ csr_dst, short* __restrict__ Y, int Nn) {
    int u = blockIdx.x;
    int tid = threadIdx.x;
    int beg = offs[u], end = offs[u + 1];
    __shared__ float w_s[2][64];
    __shared__ int dst_s[64];
    float acc0 = 0.f, acc1 = 0.f, acc2 = 0.f;
    float den0 = 0.f, den1 = 0.f;
    int c1 = tid + 256, c2 = tid + 512;
    int h1 = (c1 < UHALF) ? 0 : 1;
    float ss0 = s_src[u];
    float ss1 = s_src[Nn + u];
    for (int base = beg; base < end; base += 64) {
        int mchunk = min(64, end - base);
        if (tid < mchunk) {
            int v = csr_dst[base + tid];
            dst_s[tid] = v;
            float x0 = ss0 + s_dst[v];
            float x1 = ss1 + s_dst[Nn + v];
            x0 = (x0 >= 0.f) ? x0 : 0.2f * x0;
            x1 = (x1 >= 0.f) ? x1 : 0.2f * x1;
            x0 = fminf(fmaxf(x0, -2.f), 2.f);
            x1 = fminf(fmaxf(x1, -2.f), 2.f);
            w_s[0][tid] = expf(x0);
            w_s[1][tid] = expf(x1);
        }
        __syncthreads();
        for (int j = 0; j < mchunk; ++j) {
            int v = dst_s[j];
            const short* hv = hb + (long)v * HS;
            float w0 = w_s[0][j], w1 = w_s[1][j];
            den0 += w0;
            den1 += w1;
            acc0 += bf2f(hv[tid]) * w0;
            acc1 += bf2f(hv[c1]) * (h1 ? w1 : w0);
            if (c2 < CDIM) acc2 += bf2f(hv[c2]) * w1;
        }
        __syncthreads();
    }
    float inv0 = (den0 > 0.f) ? 1.f / den0 : 0.f;
    float inv1 = (den1 > 0.f) ? 1.f / den1 : 0.f;
    short* yrow = Y + (long)u * HS;
    yrow[tid] = f2bf(fmaxf(acc0 * inv0, 0.f));
    yrow[c1] = f2bf(fmaxf(acc1 * (h1 ? inv1 : inv0), 0.f));
    if (c2 < CDIM) yrow[c2] = f2bf(fmaxf(acc2 * inv1, 0.f));
    else if (c2 < HS) yrow[c2] = 0;
}

// ---------------- decoder (bf16 rows): out[m] = sum_c |O[r,c]-O[c,c]| * w[c] + b ----
__global__ __launch_bounds__(256) void decode_kernel(const short* __restrict__ O, const int* __restrict__ r_idx,
                                                     const int* __restrict__ c_idx, const float* __restrict__ wp,
                                                     const float* __restrict__ dec_b, float* __restrict__ out, int M) {
    int wave = threadIdx.x >> 6, lane = threadIdx.x & 63;
    long m = (long)blockIdx.x * 4 + wave;
    if (m >= M) return;
    int r = r_idx[m], c = c_idx[m];
    const short4* orow = (const short4*)(O + (long)r * HS);
    const short4* crow = (const short4*)(O + (long)c * HS);
    const float4* wv = (const float4*)wp;
    float s = 0.f;
    for (int it = lane; it < HS / 4; it += 64) {
        short4 o = orow[it];
        short4 q = crow[it];
        float4 w = wv[it];
        s += fabsf(bf2f(o.x) - bf2f(q.x)) * w.x;
        s += fabsf(bf2f(o.y) - bf2f(q.y)) * w.y;
        s += fabsf(bf2f(o.z) - bf2f(q.z)) * w.z;
        s += fabsf(bf2f(o.w) - bf2f(q.w)) * w.w;
    }
    for (int d = 32; d; d >>= 1) s += __shfl_down(s, d);
    if (lane == 0) out[m] = s + dec_b[0];
}

extern "C" void kernel_launch(void* const* d_in, const int* in_sizes, int n_in,
                              void* d_out, int out_size, void* d_ws, size_t ws_size,
                              hipStream_t stream) {
    (void)n_in; (void)out_size; (void)ws_size;
    const float* node_feats = (const float*)d_in[0];
    const int* edges = (const int*)d_in[1];
    const int* r_idx = (const int*)d_in[2];
    const int* c_idx = (const int*)d_in[3];
    const float* kmats[3] = {(const float*)d_in[4], (const float*)d_in[6], (const float*)d_in[8]};
    const float* amats[3] = {(const float*)d_in[5], (const float*)d_in[7], (const float*)d_in[9]};
    const float* dec_w = (const float*)d_in[10];
    const float* dec_b = (const float*)d_in[11];
    float* out = (float*)d_out;

    const int F0 = 256;
    const int N = in_sizes[0] / F0;
    const int E = in_sizes[1] / 2;
    const int M = in_sizes[2];
    const int KP1 = 256;
    const int KP2 = HS;   // 704

    char* ws = (char*)d_ws;
    size_t off = 0;
    auto alloc = [&](size_t bytes) -> void* {
        void* p = ws + off;
        off += (bytes + 255) & ~(size_t)255;
        return p;
    };
    short* hb   = (short*)alloc((size_t)N * HS * 2);
    short* Xb   = (short*)alloc((size_t)N * HS * 2);
    short* X0   = (short*)alloc((size_t)N * KP1 * 2);
    short* Bt   = (short*)alloc((size_t)NPAD * KP2 * 2);
    float* asrc = (float*)alloc(HS * 4);
    float* adst = (float*)alloc(HS * 4);
    float* decw = (float*)alloc(HS * 4);
    float* s_src = (float*)alloc((size_t)2 * N * 4);
    float* s_dst = (float*)alloc((size_t)2 * N * 4);
    int* offs = (int*)alloc((size_t)(N + 1) * 4);
    int* cnt = (int*)alloc((size_t)N * 4);
    int* fill = (int*)alloc((size_t)N * 4);
    int* csr_dst = (int*)alloc((size_t)E * 4);

    hipMemsetAsync(cnt, 0, (size_t)N * 4, stream);
    hipMemsetAsync(fill, 0, (size_t)N * 4, stream);

    count_kernel<<<(E + 255) / 256, 256, 0, stream>>>(edges, cnt, E);
    scan_kernel<<<1, 1024, 0, stream>>>(cnt, offs, N);
    fill_kernel<<<(E + 255) / 256, 256, 0, stream>>>(edges, offs, fill, csr_dst, E);

    long x0t = (long)N * KP1;
    cvt_bf16<<<(int)((x0t + 255) / 256), 256, 0, stream>>>(node_feats, X0, x0t);
    pack_decw<<<(HS + 255) / 256, 256, 0, stream>>>(dec_w, decw);

    for (int l = 0; l < 3; ++l) {
        int Kpad = (l == 0) ? KP1 : KP2;
        const short* X = (l == 0) ? X0 : Xb;
        long bt = (long)NPAD * Kpad;
        pack_bt<<<(int)((bt + 255) / 256), 256, 0, stream>>>(kmats[l], Bt, (l == 0) ? F0 : CDIM, Kpad);
        pack_avec<<<(HS + 255) / 256, 256, 0, stream>>>(amats[l], asrc, adst);
        dim3 g((N + GBM - 1) / GBM, NPAD / GBN);
        gemm_mfma<<<g, 256, 0, stream>>>(X, Bt, hb, N, Kpad);
        score_kernel<<<(N + 3) / 4, 256, 0, stream>>>(hb, asrc, adst, s_src, s_dst, N);
        aggregate_kernel<<<N, 256, 0, stream>>>(hb, s_src, s_dst, offs, csr_dst, Xb, N);
    }
    decode_kernel<<<(M + 3) / 4, 256, 0, stream>>>(Xb, r_idx, c_idx, decw, dec_b, out, M);
}

// Round 4
// 372.295 us; speedup vs baseline: 4.2928x; 1.1466x over previous
//
#include <hip/hip_runtime.h>

#define CDIM 700     // 2 heads * 350 units, head-concat
#define UHALF 350
#define NPAD 768     // CDIM padded to multiple of 128 (GEMM N dim)
#define HS 704       // activation row stride (bf16)
#define NBY 6        // NPAD / GBN

// GEMM tile params
#define GBM 128
#define GBN 128
#define GBK 32

typedef __attribute__((ext_vector_type(8))) short bf16x8;
typedef __attribute__((ext_vector_type(4))) float f32x4;

__device__ inline short f2bf(float v) {
    unsigned u = __float_as_uint(v);
    unsigned r = (u + 0x7fffu + ((u >> 16) & 1u)) >> 16;
    return (short)r;
}
__device__ inline float bf2f(short s) {
    return __uint_as_float(((unsigned)(unsigned short)s) << 16);
}

__device__ inline void load_lds16(const void* g, void* l) {
    __builtin_amdgcn_global_load_lds(
        (const __attribute__((address_space(1))) unsigned*)g,
        (__attribute__((address_space(3))) unsigned*)l,
        16, 0, 0);
}

// ---------------- packing / conversion ----------------
__global__ void pack_bt(const float* __restrict__ K, short* __restrict__ Bt, int Kin, int Kpad) {
    long i = (long)blockIdx.x * blockDim.x + threadIdx.x;
    long total = (long)NPAD * Kpad;
    if (i >= total) return;
    int c = (int)(i / Kpad), f = (int)(i % Kpad);
    float v = 0.f;
    if (c < CDIM && f < Kin) {
        int h = c / UHALF, u = c % UHALF;
        v = K[((long)h * Kin + f) * UHALF + u];
    }
    Bt[i] = f2bf(v);
}

__global__ void cvt_bf16(const float* __restrict__ X, short* __restrict__ Xb, long total) {
    long i = (long)blockIdx.x * blockDim.x + threadIdx.x;
    if (i >= total) return;
    Xb[i] = f2bf(X[i]);
}

__global__ void pack_avec(const float* __restrict__ A, float* __restrict__ asrc, float* __restrict__ adst) {
    int i = blockIdx.x * blockDim.x + threadIdx.x;
    if (i >= HS) return;
    if (i < CDIM) {
        int h = i / UHALF, u = i % UHALF;
        asrc[i] = A[h * 2 * UHALF + u];
        adst[i] = A[h * 2 * UHALF + UHALF + u];
    } else {
        asrc[i] = 0.f;
        adst[i] = 0.f;
    }
}

__global__ void pack_decw(const float* __restrict__ w, float* __restrict__ wp) {
    int i = blockIdx.x * blockDim.x + threadIdx.x;
    if (i >= HS) return;
    wp[i] = (i < CDIM) ? w[i] : 0.f;
}

// ---------------- CSR build (by src) ----------------
__global__ void count_kernel(const int* __restrict__ edges, int* __restrict__ cnt, int E) {
    int e = blockIdx.x * blockDim.x + threadIdx.x;
    if (e >= E) return;
    atomicAdd(&cnt[edges[2 * e]], 1);
}

__global__ void scan_kernel(const int* __restrict__ cnt, int* __restrict__ offs, int Nn) {
    __shared__ int part[1024];
    int tid = threadIdx.x;
    int chunk = (Nn + 1023) / 1024;
    int b = tid * chunk;
    int e = min(b + chunk, Nn);
    int s = 0;
    for (int i = b; i < e; ++i) s += cnt[i];
    part[tid] = s;
    __syncthreads();
    for (int d = 1; d < 1024; d <<= 1) {
        int v = (tid >= d) ? part[tid - d] : 0;
        __syncthreads();
        part[tid] += v;
        __syncthreads();
    }
    int pre = (tid == 0) ? 0 : part[tid - 1];
    for (int i = b; i < e; ++i) { offs[i] = pre; pre += cnt[i]; }
    if (tid == 0) offs[Nn] = part[1023];
}

__global__ void fill_kernel(const int* __restrict__ edges, const int* __restrict__ offs,
                            int* __restrict__ fill, int* __restrict__ csr_dst, int E) {
    int e = blockIdx.x * blockDim.x + threadIdx.x;
    if (e >= E) return;
    int s = edges[2 * e], d = edges[2 * e + 1];
    int pos = offs[s] + atomicAdd(&fill[s], 1);
    csr_dst[pos] = d;
}

// ------- bf16 MFMA GEMM, 2-phase double-buffered + XCD swizzle with A-reuse -------
__global__ __launch_bounds__(256) void gemm_mfma(const short* __restrict__ Xb, const short* __restrict__ Bt,
                                                 short* __restrict__ hb, int M, int Kpad) {
    __shared__ short sA[2][GBM * GBK];
    __shared__ short sB[2][GBN * GBK];
    int tid = threadIdx.x;
    int wave = tid >> 6, lane = tid & 63;

    // bijective XCD swizzle: contiguous wgid chunk per XCD; by inner -> 6 consecutive
    // wgids share the same A row panel on the same XCD.
    int nwg = gridDim.x;
    int id = blockIdx.x;
    int q = nwg >> 3, r = nwg & 7;
    int xcd = id & 7, rk = id >> 3;
    int wgid = (xcd < r ? xcd * (q + 1) : r * (q + 1) + (xcd - r) * q) + rk;
    int by = wgid % NBY;
    int bx = wgid / NBY;
    int brow = bx * GBM;
    int bcol = by * GBN;
    int wr = wave >> 1, wc = wave & 1;
    f32x4 acc[4][4] = {};

    int lrow = lane >> 2;
    int lkb = (lane & 3) * 8;

    // per-thread global srcs (row clamped once)
    int ga0 = brow + wave * 32 + lrow;       if (ga0 >= M) ga0 = M - 1;
    int ga1 = brow + wave * 32 + 16 + lrow;  if (ga1 >= M) ga1 = M - 1;
    const short* srcA0 = Xb + (long)ga0 * Kpad + lkb;
    const short* srcA1 = Xb + (long)ga1 * Kpad + lkb;
    const short* srcB0 = Bt + (long)(bcol + wave * 32 + lrow) * Kpad + lkb;
    const short* srcB1 = Bt + (long)(bcol + wave * 32 + 16 + lrow) * Kpad + lkb;
    int r0 = wave * 32;

#define STAGE(buf, k0)                                                   \
    do {                                                                 \
        load_lds16(srcA0 + (k0), &sA[buf][r0 * GBK]);                    \
        load_lds16(srcA1 + (k0), &sA[buf][(r0 + 16) * GBK]);             \
        load_lds16(srcB0 + (k0), &sB[buf][r0 * GBK]);                    \
        load_lds16(srcB1 + (k0), &sB[buf][(r0 + 16) * GBK]);             \
    } while (0)

    STAGE(0, 0);
    __syncthreads();

    int nt = Kpad / GBK;
    int cur = 0;
    const int aoff = (wr * 64 + (lane & 15)) * GBK + (lane >> 4) * 8;
    const int boff = (wc * 64 + (lane & 15)) * GBK + (lane >> 4) * 8;
    for (int t = 0; t < nt; ++t) {
        if (t + 1 < nt) STAGE(cur ^ 1, (t + 1) * GBK);
        const short* pa = &sA[cur][0] + aoff;
        const short* pb = &sB[cur][0] + boff;
        bf16x8 af[4], bfr[4];
#pragma unroll
        for (int m = 0; m < 4; ++m) af[m] = *(const bf16x8*)(pa + m * 16 * GBK);
#pragma unroll
        for (int n = 0; n < 4; ++n) bfr[n] = *(const bf16x8*)(pb + n * 16 * GBK);
        __builtin_amdgcn_s_setprio(1);
#pragma unroll
        for (int m = 0; m < 4; ++m)
#pragma unroll
            for (int n = 0; n < 4; ++n)
                acc[m][n] = __builtin_amdgcn_mfma_f32_16x16x32_bf16(af[m], bfr[n], acc[m][n], 0, 0, 0);
        __builtin_amdgcn_s_setprio(0);
        __syncthreads();   // drains vmcnt(0)+lgkmcnt(0): next buffer staged, reads done
        cur ^= 1;
    }
#undef STAGE

    int crow = brow + wr * 64 + (lane >> 4) * 4;
    int ccol = bcol + wc * 64 + (lane & 15);
#pragma unroll
    for (int m = 0; m < 4; ++m) {
#pragma unroll
        for (int rr = 0; rr < 4; ++rr) {
            int gr = crow + m * 16 + rr;
            if (gr >= M) continue;
#pragma unroll
            for (int n = 0; n < 4; ++n) {
                int gc = ccol + n * 16;
                if (gc < CDIM) hb[(long)gr * HS + gc] = f2bf(acc[m][n][rr]);
            }
        }
    }
}

// ---------------- per-node attention scores ----------------
__global__ __launch_bounds__(256) void score_kernel(const short* __restrict__ hb, const float* __restrict__ asrc,
                                                    const float* __restrict__ adst, float* __restrict__ s_src,
                                                    float* __restrict__ s_dst, int Nn) {
    int wave = threadIdx.x >> 6, lane = threadIdx.x & 63;
    int u = blockIdx.x * 4 + wave;
    if (u >= Nn) return;
    const short4* hrow = (const short4*)(hb + (long)u * HS);
    float ps0 = 0.f, pd0 = 0.f, ps1 = 0.f, pd1 = 0.f;
    for (int it = lane; it < HS / 4; it += 64) {
        short4 v = hrow[it];
        int col = it * 4;
#pragma unroll
        for (int e = 0; e < 4; ++e) {
            float f = bf2f(((const short*)&v)[e]);
            int c = col + e;
            float a = asrc[c], d = adst[c];
            if (c < UHALF) { ps0 += f * a; pd0 += f * d; }
            else           { ps1 += f * a; pd1 += f * d; }
        }
    }
    for (int d = 32; d; d >>= 1) {
        ps0 += __shfl_down(ps0, d); pd0 += __shfl_down(pd0, d);
        ps1 += __shfl_down(ps1, d); pd1 += __shfl_down(pd1, d);
    }
    if (lane == 0) {
        s_src[u] = ps0; s_dst[u] = pd0;
        s_src[Nn + u] = ps1; s_dst[Nn + u] = pd1;
    }
}

// -------- per-node aggregation: 4-way edge-parallel waves + LDS reduce --------
__global__ __launch_bounds__(256) void aggregate_kernel(const short* __restrict__ hb, const float* __restrict__ s_src,
                                                        const float* __restrict__ s_dst, const int* __restrict__ offs,
                                                        const int* __restrict__ csr_dst, short* __restrict__ Y, int Nn) {
    int u = blockIdx.x;
    int tid = threadIdx.x;
    int wave = tid >> 6, lane = tid & 63;
    int beg = offs[u], end = offs[u + 1];
    __shared__ float redbuf[4][HS];
    __shared__ float dred[4][2];

    float ss0 = s_src[u];
    float ss1 = s_src[Nn + u];
    f32x4 facc[3] = {};
    float den0 = 0.f, den1 = 0.f;

    int it0 = lane, it1 = lane + 64, it2 = lane + 128;  // short4 indices, HS/4=176
    for (int e = beg + wave; e < end; e += 4) {
        int v = csr_dst[e];
        float x0 = ss0 + s_dst[v];
        float x1 = ss1 + s_dst[Nn + v];
        x0 = (x0 >= 0.f) ? x0 : 0.2f * x0;
        x1 = (x1 >= 0.f) ? x1 : 0.2f * x1;
        x0 = fminf(fmaxf(x0, -2.f), 2.f);
        x1 = fminf(fmaxf(x1, -2.f), 2.f);
        float w0 = expf(x0), w1 = expf(x1);
        den0 += w0; den1 += w1;
        const short4* hv = (const short4*)(hb + (long)v * HS);
        short4 v0 = hv[it0];
        short4 v1 = hv[it1];
        short4 v2 = (it2 < HS / 4) ? hv[it2] : make_short4(0, 0, 0, 0);
#pragma unroll
        for (int ee = 0; ee < 4; ++ee) {
            int c0 = it0 * 4 + ee, c1 = it1 * 4 + ee, c2 = it2 * 4 + ee;
            facc[0][ee] += bf2f(((const short*)&v0)[ee]) * ((c0 < UHALF) ? w0 : w1);
            facc[1][ee] += bf2f(((const short*)&v1)[ee]) * ((c1 < UHALF) ? w0 : w1);
            facc[2][ee] += bf2f(((const short*)&v2)[ee]) * ((c2 < UHALF) ? w0 : w1);
        }
    }
    *(f32x4*)&redbuf[wave][it0 * 4] = facc[0];
    *(f32x4*)&redbuf[wave][it1 * 4] = facc[1];
    if (it2 < HS / 4) *(f32x4*)&redbuf[wave][it2 * 4] = facc[2];
    if (lane == 0) { dred[wave][0] = den0; dred[wave][1] = den1; }
    __syncthreads();

    float d0 = dred[0][0] + dred[1][0] + dred[2][0] + dred[3][0];
    float d1 = dred[0][1] + dred[1][1] + dred[2][1] + dred[3][1];
    float inv0 = (d0 > 0.f) ? 1.f / d0 : 0.f;
    float inv1 = (d1 > 0.f) ? 1.f / d1 : 0.f;
    short* yrow = Y + (long)u * HS;
    int c1 = tid + 256, c2 = tid + 512;
    float a0 = redbuf[0][tid] + redbuf[1][tid] + redbuf[2][tid] + redbuf[3][tid];
    float a1 = redbuf[0][c1] + redbuf[1][c1] + redbuf[2][c1] + redbuf[3][c1];
    yrow[tid] = f2bf(fmaxf(a0 * ((tid < UHALF) ? inv0 : inv1), 0.f));
    yrow[c1] = f2bf(fmaxf(a1 * ((c1 < UHALF) ? inv0 : inv1), 0.f));
    if (c2 < HS) {
        float a2 = redbuf[0][c2] + redbuf[1][c2] + redbuf[2][c2] + redbuf[3][c2];
        yrow[c2] = (c2 < CDIM) ? f2bf(fmaxf(a2 * inv1, 0.f)) : (short)0;
    }
}

// ---------------- decoder ----------------
__global__ __launch_bounds__(256) void decode_kernel(const short* __restrict__ O, const int* __restrict__ r_idx,
                                                     const int* __restrict__ c_idx, const float* __restrict__ wp,
                                                     const float* __restrict__ dec_b, float* __restrict__ out, int M) {
    int wave = threadIdx.x >> 6, lane = threadIdx.x & 63;
    long m = (long)blockIdx.x * 4 + wave;
    if (m >= M) return;
    int r = r_idx[m], c = c_idx[m];
    const short4* orow = (const short4*)(O + (long)r * HS);
    const short4* crow = (const short4*)(O + (long)c * HS);
    const float4* wv = (const float4*)wp;
    float s = 0.f;
    for (int it = lane; it < HS / 4; it += 64) {
        short4 o = orow[it];
        short4 q = crow[it];
        float4 w = wv[it];
        s += fabsf(bf2f(o.x) - bf2f(q.x)) * w.x;
        s += fabsf(bf2f(o.y) - bf2f(q.y)) * w.y;
        s += fabsf(bf2f(o.z) - bf2f(q.z)) * w.z;
        s += fabsf(bf2f(o.w) - bf2f(q.w)) * w.w;
    }
    for (int d = 32; d; d >>= 1) s += __shfl_down(s, d);
    if (lane == 0) out[m] = s + dec_b[0];
}

extern "C" void kernel_launch(void* const* d_in, const int* in_sizes, int n_in,
                              void* d_out, int out_size, void* d_ws, size_t ws_size,
                              hipStream_t stream) {
    (void)n_in; (void)out_size; (void)ws_size;
    const float* node_feats = (const float*)d_in[0];
    const int* edges = (const int*)d_in[1];
    const int* r_idx = (const int*)d_in[2];
    const int* c_idx = (const int*)d_in[3];
    const float* kmats[3] = {(const float*)d_in[4], (const float*)d_in[6], (const float*)d_in[8]};
    const float* amats[3] = {(const float*)d_in[5], (const float*)d_in[7], (const float*)d_in[9]};
    const float* dec_w = (const float*)d_in[10];
    const float* dec_b = (const float*)d_in[11];
    float* out = (float*)d_out;

    const int F0 = 256;
    const int N = in_sizes[0] / F0;
    const int E = in_sizes[1] / 2;
    const int M = in_sizes[2];
    const int KP1 = 256;
    const int KP2 = HS;   // 704

    char* ws = (char*)d_ws;
    size_t off = 0;
    auto alloc = [&](size_t bytes) -> void* {
        void* p = ws + off;
        off += (bytes + 255) & ~(size_t)255;
        return p;
    };
    short* hb   = (short*)alloc((size_t)N * HS * 2);
    short* Xb   = (short*)alloc((size_t)N * HS * 2);
    short* X0   = (short*)alloc((size_t)N * KP1 * 2);
    short* Bt   = (short*)alloc((size_t)NPAD * KP2 * 2);
    float* asrc = (float*)alloc(HS * 4);
    float* adst = (float*)alloc(HS * 4);
    float* decw = (float*)alloc(HS * 4);
    float* s_src = (float*)alloc((size_t)2 * N * 4);
    float* s_dst = (float*)alloc((size_t)2 * N * 4);
    int* offs = (int*)alloc((size_t)(N + 1) * 4);
    int* cnt = (int*)alloc((size_t)N * 4);
    int* fill = (int*)alloc((size_t)N * 4);
    int* csr_dst = (int*)alloc((size_t)E * 4);

    hipMemsetAsync(cnt, 0, (size_t)N * 4, stream);
    hipMemsetAsync(fill, 0, (size_t)N * 4, stream);

    count_kernel<<<(E + 255) / 256, 256, 0, stream>>>(edges, cnt, E);
    scan_kernel<<<1, 1024, 0, stream>>>(cnt, offs, N);
    fill_kernel<<<(E + 255) / 256, 256, 0, stream>>>(edges, offs, fill, csr_dst, E);

    long x0t = (long)N * KP1;
    cvt_bf16<<<(int)((x0t + 255) / 256), 256, 0, stream>>>(node_feats, X0, x0t);
    pack_decw<<<(HS + 255) / 256, 256, 0, stream>>>(dec_w, decw);

    for (int l = 0; l < 3; ++l) {
        int Kpad = (l == 0) ? KP1 : KP2;
        const short* X = (l == 0) ? X0 : Xb;
        long bt = (long)NPAD * Kpad;
        pack_bt<<<(int)((bt + 255) / 256), 256, 0, stream>>>(kmats[l], Bt, (l == 0) ? F0 : CDIM, Kpad);
        pack_avec<<<(HS + 255) / 256, 256, 0, stream>>>(amats[l], asrc, adst);
        int nbx = (N + GBM - 1) / GBM;
        gemm_mfma<<<nbx * NBY, 256, 0, stream>>>(X, Bt, hb, N, Kpad);
        score_kernel<<<(N + 3) / 4, 256, 0, stream>>>(hb, asrc, adst, s_src, s_dst, N);
        aggregate_kernel<<<N, 256, 0, stream>>>(hb, s_src, s_dst, offs, csr_dst, Xb, N);
    }
    decode_kernel<<<(M + 3) / 4, 256, 0, stream>>>(Xb, r_idx, c_idx, decw, dec_b, out, M);
}

// Round 5
// 369.494 us; speedup vs baseline: 4.3254x; 1.0076x over previous
//
#include <hip/hip_runtime.h>

#define CDIM 700     // 2 heads * 350 units, head-concat
#define UHALF 350
#define NPAD 768     // CDIM padded to multiple of 128 (GEMM N dim)
#define HS 704       // activation row stride (bf16)
#define NBY 6        // NPAD / GBN

// GEMM tile params
#define GBM 128
#define GBN 128
#define GBK 32

typedef __attribute__((ext_vector_type(8))) short bf16x8;
typedef __attribute__((ext_vector_type(4))) float f32x4;

__device__ inline short f2bf(float v) {
    unsigned u = __float_as_uint(v);
    unsigned r = (u + 0x7fffu + ((u >> 16) & 1u)) >> 16;
    return (short)r;
}
__device__ inline float bf2f(short s) {
    return __uint_as_float(((unsigned)(unsigned short)s) << 16);
}

__device__ inline void load_lds16(const void* g, void* l) {
    __builtin_amdgcn_global_load_lds(
        (const __attribute__((address_space(1))) unsigned*)g,
        (__attribute__((address_space(3))) unsigned*)l,
        16, 0, 0);
}

#define WAITV8() asm volatile("s_waitcnt vmcnt(8)" ::: "memory")
#define WAITV0() asm volatile("s_waitcnt vmcnt(0)" ::: "memory")
#define FENCE()  asm volatile("" ::: "memory")

// ---------------- packing / conversion ----------------
__global__ void pack_bt(const float* __restrict__ K, short* __restrict__ Bt, int Kin, int Kpad) {
    long i = (long)blockIdx.x * blockDim.x + threadIdx.x;
    long total = (long)NPAD * Kpad;
    if (i >= total) return;
    int c = (int)(i / Kpad), f = (int)(i % Kpad);
    float v = 0.f;
    if (c < CDIM && f < Kin) {
        int h = c / UHALF, u = c % UHALF;
        v = K[((long)h * Kin + f) * UHALF + u];
    }
    Bt[i] = f2bf(v);
}

__global__ void cvt_bf16(const float* __restrict__ X, short* __restrict__ Xb, long total) {
    long i = (long)blockIdx.x * blockDim.x + threadIdx.x;
    if (i >= total) return;
    Xb[i] = f2bf(X[i]);
}

__global__ void pack_avec(const float* __restrict__ A, float* __restrict__ asrc, float* __restrict__ adst) {
    int i = blockIdx.x * blockDim.x + threadIdx.x;
    if (i >= HS) return;
    if (i < CDIM) {
        int h = i / UHALF, u = i % UHALF;
        asrc[i] = A[h * 2 * UHALF + u];
        adst[i] = A[h * 2 * UHALF + UHALF + u];
    } else {
        asrc[i] = 0.f;
        adst[i] = 0.f;
    }
}

__global__ void pack_decw(const float* __restrict__ w, float* __restrict__ wp) {
    int i = blockIdx.x * blockDim.x + threadIdx.x;
    if (i >= HS) return;
    wp[i] = (i < CDIM) ? w[i] : 0.f;
}

// ---------------- CSR build (by src) ----------------
__global__ void count_kernel(const int* __restrict__ edges, int* __restrict__ cnt, int E) {
    int e = blockIdx.x * blockDim.x + threadIdx.x;
    if (e >= E) return;
    atomicAdd(&cnt[edges[2 * e]], 1);
}

__global__ void scan_kernel(const int* __restrict__ cnt, int* __restrict__ offs, int Nn) {
    __shared__ int part[1024];
    int tid = threadIdx.x;
    int chunk = (Nn + 1023) / 1024;
    int b = tid * chunk;
    int e = min(b + chunk, Nn);
    int s = 0;
    for (int i = b; i < e; ++i) s += cnt[i];
    part[tid] = s;
    __syncthreads();
    for (int d = 1; d < 1024; d <<= 1) {
        int v = (tid >= d) ? part[tid - d] : 0;
        __syncthreads();
        part[tid] += v;
        __syncthreads();
    }
    int pre = (tid == 0) ? 0 : part[tid - 1];
    for (int i = b; i < e; ++i) { offs[i] = pre; pre += cnt[i]; }
    if (tid == 0) offs[Nn] = part[1023];
}

__global__ void fill_kernel(const int* __restrict__ edges, const int* __restrict__ offs,
                            int* __restrict__ fill, int* __restrict__ csr_dst, int E) {
    int e = blockIdx.x * blockDim.x + threadIdx.x;
    if (e >= E) return;
    int s = edges[2 * e], d = edges[2 * e + 1];
    int pos = offs[s] + atomicAdd(&fill[s], 1);
    csr_dst[pos] = d;
}

// ------- bf16 MFMA GEMM: counted-vmcnt pipeline + XOR-swizzled LDS + XCD swizzle -------
__global__ __launch_bounds__(256) void gemm_mfma(const short* __restrict__ Xb, const short* __restrict__ Bt,
                                                 short* __restrict__ hb, int M, int Kpad) {
    __shared__ short sA[2][GBM * GBK];
    __shared__ short sB[2][GBN * GBK];
    int tid = threadIdx.x;
    int wave = tid >> 6, lane = tid & 63;

    // bijective XCD swizzle; by inner -> 6 consecutive wgids share A row panel per XCD
    int nwg = gridDim.x;
    int id = blockIdx.x;
    int q = nwg >> 3, r = nwg & 7;
    int xcd = id & 7, rk = id >> 3;
    int wgid = (xcd < r ? xcd * (q + 1) : r * (q + 1) + (xcd - r) * q) + rk;
    int by = wgid % NBY;
    int bx = wgid / NBY;
    int brow = bx * GBM;
    int bcol = by * GBN;
    int wr = wave >> 1, wc = wave & 1;
    f32x4 acc[4][4] = {};

    int lrow = lane >> 2;
    // swizzled source k-slot: data for LDS (row, slot) comes from global slot^((row>>1)&3);
    // with row = r0 + (lane>>2), r0 % 16 == 0 -> swz bits = (lane>>3)&3
    int lkb = (((lane & 3) ^ ((lane >> 3) & 3)) * 8);

    int ga0 = brow + wave * 32 + lrow;       if (ga0 >= M) ga0 = M - 1;
    int ga1 = brow + wave * 32 + 16 + lrow;  if (ga1 >= M) ga1 = M - 1;
    const short* srcA0 = Xb + (long)ga0 * Kpad + lkb;
    const short* srcA1 = Xb + (long)ga1 * Kpad + lkb;
    const short* srcB0 = Bt + (long)(bcol + wave * 32 + lrow) * Kpad + lkb;
    const short* srcB1 = Bt + (long)(bcol + wave * 32 + 16 + lrow) * Kpad + lkb;
    int r0 = wave * 32;

#define STAGE(buf, k0)                                                   \
    do {                                                                 \
        load_lds16(srcA0 + (k0), &sA[buf][r0 * GBK]);                    \
        load_lds16(srcA1 + (k0), &sA[buf][(r0 + 16) * GBK]);             \
        load_lds16(srcB0 + (k0), &sB[buf][r0 * GBK]);                    \
        load_lds16(srcB1 + (k0), &sB[buf][(r0 + 16) * GBK]);             \
    } while (0)

    STAGE(0, 0);

    int nt = Kpad / GBK;
    int cur = 0;
    // swizzled read slot: (lane>>4) ^ ((row>>1)&3), row = sub + (lane&15) + 16m
    // -> ((lane&15)>>1)&3 = (lane>>1)&3, constant per lane across m
    const int slotR = ((lane >> 4) ^ ((lane >> 1) & 3)) * 8;
    const int aoff = (wr * 64 + (lane & 15)) * GBK + slotR;
    const int boff = (wc * 64 + (lane & 15)) * GBK + slotR;

    for (int t = 0; t < nt; ++t) {
        if (t + 1 < nt) {
            STAGE(cur ^ 1, (t + 1) * GBK);
            WAITV8();            // tile t landed; tile t+1's 8 loads stay in flight
        } else {
            WAITV0();            // last tile: full drain
        }
        __builtin_amdgcn_s_barrier();
        __builtin_amdgcn_sched_barrier(0);

        const short* pa = &sA[cur][0] + aoff;
        const short* pb = &sB[cur][0] + boff;
        bf16x8 af[4], bfr[4];
#pragma unroll
        for (int m = 0; m < 4; ++m) af[m] = *(const bf16x8*)(pa + m * 16 * GBK);
#pragma unroll
        for (int n = 0; n < 4; ++n) bfr[n] = *(const bf16x8*)(pb + n * 16 * GBK);
        __builtin_amdgcn_s_setprio(1);
#pragma unroll
        for (int m = 0; m < 4; ++m)
#pragma unroll
            for (int n = 0; n < 4; ++n)
                acc[m][n] = __builtin_amdgcn_mfma_f32_16x16x32_bf16(af[m], bfr[n], acc[m][n], 0, 0, 0);
        __builtin_amdgcn_s_setprio(0);

        if (t + 1 < nt) {        // reads of buf[cur] done before t+1's STAGE overwrites it
            FENCE();
            __builtin_amdgcn_s_barrier();
            __builtin_amdgcn_sched_barrier(0);
        }
        cur ^= 1;
    }
#undef STAGE

    int crow = brow + wr * 64 + (lane >> 4) * 4;
    int ccol = bcol + wc * 64 + (lane & 15);
#pragma unroll
    for (int m = 0; m < 4; ++m) {
#pragma unroll
        for (int rr = 0; rr < 4; ++rr) {
            int gr = crow + m * 16 + rr;
            if (gr >= M) continue;
#pragma unroll
            for (int n = 0; n < 4; ++n) {
                int gc = ccol + n * 16;
                if (gc < CDIM) hb[(long)gr * HS + gc] = f2bf(acc[m][n][rr]);
            }
        }
    }
}

// ---------------- per-node attention scores ----------------
__global__ __launch_bounds__(256) void score_kernel(const short* __restrict__ hb, const float* __restrict__ asrc,
                                                    const float* __restrict__ adst, float* __restrict__ s_src,
                                                    float* __restrict__ s_dst, int Nn) {
    int wave = threadIdx.x >> 6, lane = threadIdx.x & 63;
    int u = blockIdx.x * 4 + wave;
    if (u >= Nn) return;
    const short4* hrow = (const short4*)(hb + (long)u * HS);
    float ps0 = 0.f, pd0 = 0.f, ps1 = 0.f, pd1 = 0.f;
    for (int it = lane; it < HS / 4; it += 64) {
        short4 v = hrow[it];
        int col = it * 4;
#pragma unroll
        for (int e = 0; e < 4; ++e) {
            float f = bf2f(((const short*)&v)[e]);
            int c = col + e;
            float a = asrc[c], d = adst[c];
            if (c < UHALF) { ps0 += f * a; pd0 += f * d; }
            else           { ps1 += f * a; pd1 += f * d; }
        }
    }
    for (int d = 32; d; d >>= 1) {
        ps0 += __shfl_down(ps0, d); pd0 += __shfl_down(pd0, d);
        ps1 += __shfl_down(ps1, d); pd1 += __shfl_down(pd1, d);
    }
    if (lane == 0) {
        s_src[u] = ps0; s_dst[u] = pd0;
        s_src[Nn + u] = ps1; s_dst[Nn + u] = pd1;
    }
}

// -------- per-node aggregation: 4-way edge-parallel waves + LDS reduce --------
__global__ __launch_bounds__(256) void aggregate_kernel(const short* __restrict__ hb, const float* __restrict__ s_src,
                                                        const float* __restrict__ s_dst, const int* __restrict__ offs,
                                                        const int* __restrict__ csr_dst, short* __restrict__ Y, int Nn) {
    int u = blockIdx.x;
    int tid = threadIdx.x;
    int wave = tid >> 6, lane = tid & 63;
    int beg = offs[u], end = offs[u + 1];
    __shared__ float redbuf[4][HS];
    __shared__ float dred[4][2];

    float ss0 = s_src[u];
    float ss1 = s_src[Nn + u];
    f32x4 facc[3] = {};
    float den0 = 0.f, den1 = 0.f;

    int it0 = lane, it1 = lane + 64, it2 = lane + 128;  // short4 indices, HS/4=176
    for (int e = beg + wave; e < end; e += 4) {
        int v = csr_dst[e];
        float x0 = ss0 + s_dst[v];
        float x1 = ss1 + s_dst[Nn + v];
        x0 = (x0 >= 0.f) ? x0 : 0.2f * x0;
        x1 = (x1 >= 0.f) ? x1 : 0.2f * x1;
        x0 = fminf(fmaxf(x0, -2.f), 2.f);
        x1 = fminf(fmaxf(x1, -2.f), 2.f);
        float w0 = expf(x0), w1 = expf(x1);
        den0 += w0; den1 += w1;
        const short4* hv = (const short4*)(hb + (long)v * HS);
        short4 v0 = hv[it0];
        short4 v1 = hv[it1];
        short4 v2 = (it2 < HS / 4) ? hv[it2] : make_short4(0, 0, 0, 0);
#pragma unroll
        for (int ee = 0; ee < 4; ++ee) {
            int c0 = it0 * 4 + ee, c1 = it1 * 4 + ee, c2 = it2 * 4 + ee;
            facc[0][ee] += bf2f(((const short*)&v0)[ee]) * ((c0 < UHALF) ? w0 : w1);
            facc[1][ee] += bf2f(((const short*)&v1)[ee]) * ((c1 < UHALF) ? w0 : w1);
            facc[2][ee] += bf2f(((const short*)&v2)[ee]) * ((c2 < UHALF) ? w0 : w1);
        }
    }
    *(f32x4*)&redbuf[wave][it0 * 4] = facc[0];
    *(f32x4*)&redbuf[wave][it1 * 4] = facc[1];
    if (it2 < HS / 4) *(f32x4*)&redbuf[wave][it2 * 4] = facc[2];
    if (lane == 0) { dred[wave][0] = den0; dred[wave][1] = den1; }
    __syncthreads();

    float d0 = dred[0][0] + dred[1][0] + dred[2][0] + dred[3][0];
    float d1 = dred[0][1] + dred[1][1] + dred[2][1] + dred[3][1];
    float inv0 = (d0 > 0.f) ? 1.f / d0 : 0.f;
    float inv1 = (d1 > 0.f) ? 1.f / d1 : 0.f;
    short* yrow = Y + (long)u * HS;
    int c1 = tid + 256, c2 = tid + 512;
    float a0 = redbuf[0][tid] + redbuf[1][tid] + redbuf[2][tid] + redbuf[3][tid];
    float a1 = redbuf[0][c1] + redbuf[1][c1] + redbuf[2][c1] + redbuf[3][c1];
    yrow[tid] = f2bf(fmaxf(a0 * ((tid < UHALF) ? inv0 : inv1), 0.f));
    yrow[c1] = f2bf(fmaxf(a1 * ((c1 < UHALF) ? inv0 : inv1), 0.f));
    if (c2 < HS) {
        float a2 = redbuf[0][c2] + redbuf[1][c2] + redbuf[2][c2] + redbuf[3][c2];
        yrow[c2] = (c2 < CDIM) ? f2bf(fmaxf(a2 * inv1, 0.f)) : (short)0;
    }
}

// ---------------- decoder ----------------
__global__ __launch_bounds__(256) void decode_kernel(const short* __restrict__ O, const int* __restrict__ r_idx,
                                                     const int* __restrict__ c_idx, const float* __restrict__ wp,
                                                     const float* __restrict__ dec_b, float* __restrict__ out, int M) {
    int wave = threadIdx.x >> 6, lane = threadIdx.x & 63;
    long m = (long)blockIdx.x * 4 + wave;
    if (m >= M) return;
    int r = r_idx[m], c = c_idx[m];
    const short4* orow = (const short4*)(O + (long)r * HS);
    const short4* crow = (const short4*)(O + (long)c * HS);
    const float4* wv = (const float4*)wp;
    float s = 0.f;
    for (int it = lane; it < HS / 4; it += 64) {
        short4 o = orow[it];
        short4 q = crow[it];
        float4 w = wv[it];
        s += fabsf(bf2f(o.x) - bf2f(q.x)) * w.x;
        s += fabsf(bf2f(o.y) - bf2f(q.y)) * w.y;
        s += fabsf(bf2f(o.z) - bf2f(q.z)) * w.z;
        s += fabsf(bf2f(o.w) - bf2f(q.w)) * w.w;
    }
    for (int d = 32; d; d >>= 1) s += __shfl_down(s, d);
    if (lane == 0) out[m] = s + dec_b[0];
}

extern "C" void kernel_launch(void* const* d_in, const int* in_sizes, int n_in,
                              void* d_out, int out_size, void* d_ws, size_t ws_size,
                              hipStream_t stream) {
    (void)n_in; (void)out_size; (void)ws_size;
    const float* node_feats = (const float*)d_in[0];
    const int* edges = (const int*)d_in[1];
    const int* r_idx = (const int*)d_in[2];
    const int* c_idx = (const int*)d_in[3];
    const float* kmats[3] = {(const float*)d_in[4], (const float*)d_in[6], (const float*)d_in[8]};
    const float* amats[3] = {(const float*)d_in[5], (const float*)d_in[7], (const float*)d_in[9]};
    const float* dec_w = (const float*)d_in[10];
    const float* dec_b = (const float*)d_in[11];
    float* out = (float*)d_out;

    const int F0 = 256;
    const int N = in_sizes[0] / F0;
    const int E = in_sizes[1] / 2;
    const int M = in_sizes[2];
    const int KP1 = 256;
    const int KP2 = HS;   // 704

    char* ws = (char*)d_ws;
    size_t off = 0;
    auto alloc = [&](size_t bytes) -> void* {
        void* p = ws + off;
        off += (bytes + 255) & ~(size_t)255;
        return p;
    };
    short* hb   = (short*)alloc((size_t)N * HS * 2);
    short* Xb   = (short*)alloc((size_t)N * HS * 2);
    short* X0   = (short*)alloc((size_t)N * KP1 * 2);
    short* Bt   = (short*)alloc((size_t)NPAD * KP2 * 2);
    float* asrc = (float*)alloc(HS * 4);
    float* adst = (float*)alloc(HS * 4);
    float* decw = (float*)alloc(HS * 4);
    float* s_src = (float*)alloc((size_t)2 * N * 4);
    float* s_dst = (float*)alloc((size_t)2 * N * 4);
    int* offs = (int*)alloc((size_t)(N + 1) * 4);
    int* cnt = (int*)alloc((size_t)N * 4);
    int* fill = (int*)alloc((size_t)N * 4);
    int* csr_dst = (int*)alloc((size_t)E * 4);

    hipMemsetAsync(cnt, 0, (size_t)N * 4, stream);
    hipMemsetAsync(fill, 0, (size_t)N * 4, stream);

    count_kernel<<<(E + 255) / 256, 256, 0, stream>>>(edges, cnt, E);
    scan_kernel<<<1, 1024, 0, stream>>>(cnt, offs, N);
    fill_kernel<<<(E + 255) / 256, 256, 0, stream>>>(edges, offs, fill, csr_dst, E);

    long x0t = (long)N * KP1;
    cvt_bf16<<<(int)((x0t + 255) / 256), 256, 0, stream>>>(node_feats, X0, x0t);
    pack_decw<<<(HS + 255) / 256, 256, 0, stream>>>(dec_w, decw);

    for (int l = 0; l < 3; ++l) {
        int Kpad = (l == 0) ? KP1 : KP2;
        const short* X = (l == 0) ? X0 : Xb;
        long bt = (long)NPAD * Kpad;
        pack_bt<<<(int)((bt + 255) / 256), 256, 0, stream>>>(kmats[l], Bt, (l == 0) ? F0 : CDIM, Kpad);
        pack_avec<<<(HS + 255) / 256, 256, 0, stream>>>(amats[l], asrc, adst);
        int nbx = (N + GBM - 1) / GBM;
        gemm_mfma<<<nbx * NBY, 256, 0, stream>>>(X, Bt, hb, N, Kpad);
        score_kernel<<<(N + 3) / 4, 256, 0, stream>>>(hb, asrc, adst, s_src, s_dst, N);
        aggregate_kernel<<<N, 256, 0, stream>>>(hb, s_src, s_dst, offs, csr_dst, Xb, N);
    }
    decode_kernel<<<(M + 3) / 4, 256, 0, stream>>>(Xb, r_idx, c_idx, decw, dec_b, out, M);
}